// Round 9
// baseline (157.848 us; speedup 1.0000x reference)
//
#include <hip/hip_runtime.h>
#include <hip/hip_bf16.h>

typedef __bf16 bf16_t;
typedef __bf16 bf16x8 __attribute__((ext_vector_type(8)));
typedef __bf16 bf16x4 __attribute__((ext_vector_type(4)));
typedef float f32x4 __attribute__((ext_vector_type(4)));

#define FDIM 512
#define BM 32
#define NTHR 512

// Kernel 1: Qt[g][f] = bf16(Q[f][g]) via LDS-tiled transpose (coalesced both sides)
__global__ void qtrans_kernel(const float* __restrict__ Q, bf16_t* __restrict__ Qt) {
    __shared__ float t[32][33];
    int tx = threadIdx.x & 31;
    int ty = threadIdx.x >> 5;
    int f0 = blockIdx.x * 32;
    int g0 = blockIdx.y * 32;
#pragma unroll
    for (int i = 0; i < 4; ++i)
        t[ty + 8 * i][tx] = Q[(size_t)(f0 + ty + 8 * i) * FDIM + g0 + tx];
    __syncthreads();
#pragma unroll
    for (int i = 0; i < 4; ++i)
        Qt[(size_t)(g0 + ty + 8 * i) * FDIM + f0 + tx] = (bf16_t)t[tx][ty + 8 * i];
}

// Kernel 2: out[b] = sum_g (x Q)[b,g] * x[b,g]
// MAX-TLP design: 512 thr = 8 waves, BM=32, VGPR<=64, LDS 33 KB
// -> 4 blocks/CU x 8 waves = 32 waves/CU (8/SIMD). Latency hidden by TLP,
// not ILP: no prefetch, unroll-1 K loop, minimal register footprint.
// Wave w owns col-pairs {w, 15-w} (17 K-steps, balanced), K-outermost:
// A-frags loaded once per K-step, shared across the wave's active columns.
__global__ __launch_bounds__(NTHR, 8) void bilinear_kernel(
    const float* __restrict__ x, const bf16_t* __restrict__ Qt,
    float* __restrict__ out)
{
    __shared__ bf16_t xs[BM * FDIM];   // 32 KB, swizzled: e ^= (row&15)<<3
    __shared__ float rsum[8][BM];      // 1 KB

    const int tid = threadIdx.x;
    const size_t blk = (size_t)blockIdx.x * BM;
    const float4* xin = (const float4*)(x + blk * FDIM);

    // ---- stage x: 8 float4/thread in 2 batches of 4 (max 16 payload VGPRs) ----
#pragma unroll 1
    for (int it = 0; it < 2; ++it) {
        float4 vv[4];
#pragma unroll
        for (int j = 0; j < 4; ++j) vv[j] = xin[(it * 4 + j) * NTHR + tid];
#pragma unroll
        for (int j = 0; j < 4; ++j) {
            int e = ((it * 4 + j) * NTHR + tid) * 4;
            int row = e >> 9;
            int se = e ^ ((row & 15) << 3);
            bf16x4 b;
            b[0] = (bf16_t)vv[j].x; b[1] = (bf16_t)vv[j].y;
            b[2] = (bf16_t)vv[j].z; b[3] = (bf16_t)vv[j].w;
            *(bf16x4*)(xs + se) = b;
        }
        __builtin_amdgcn_sched_barrier(0);
    }
    __syncthreads();

    const int w   = tid >> 6;
    const int l   = tid & 63;
    const int col = l & 15;
    const int kg  = l >> 4;

    const int p0 = w;        // active for ks <= w
    const int p1 = 15 - w;   // active for ks <= 15-w

    f32x4 acc[2][2][2];      // [pair][16-col half][row-tile] = 32 regs
#pragma unroll
    for (int pi = 0; pi < 2; ++pi)
#pragma unroll
        for (int h = 0; h < 2; ++h)
#pragma unroll
            for (int m = 0; m < 2; ++m)
#pragma unroll
                for (int j = 0; j < 4; ++j) acc[pi][h][m][j] = 0.0f;

    const bf16_t* qb0 = Qt + (size_t)(p0 * 32 + col) * FDIM + kg * 8;
    const bf16_t* qb1 = Qt + (size_t)(p1 * 32 + col) * FDIM + kg * 8;

    const int rb0 = col * FDIM + kg * 8;          // row = col       (m=0)
    const int rb1 = (16 + col) * FDIM + kg * 8;   // row = 16+col    (m=1)
    const int amask = col << 3;                   // (row&15)<<3, same for both

#pragma unroll 1
    for (int ks = 0; ks < 16; ++ks) {
        bf16x8 a0 = *(const bf16x8*)(xs + ((rb0 + ks * 32) ^ amask));
        bf16x8 a1 = *(const bf16x8*)(xs + ((rb1 + ks * 32) ^ amask));

        if (ks <= p0) {
#pragma unroll
            for (int h = 0; h < 2; ++h) {
                bf16x8 b = *(const bf16x8*)(qb0 + h * 16 * FDIM + ks * 32);
                acc[0][h][0] = __builtin_amdgcn_mfma_f32_16x16x32_bf16(a0, b, acc[0][h][0], 0, 0, 0);
                acc[0][h][1] = __builtin_amdgcn_mfma_f32_16x16x32_bf16(a1, b, acc[0][h][1], 0, 0, 0);
            }
        }
        if (ks <= p1) {
#pragma unroll
            for (int h = 0; h < 2; ++h) {
                bf16x8 b = *(const bf16x8*)(qb1 + h * 16 * FDIM + ks * 32);
                acc[1][h][0] = __builtin_amdgcn_mfma_f32_16x16x32_bf16(a0, b, acc[1][h][0], 0, 0, 0);
                acc[1][h][1] = __builtin_amdgcn_mfma_f32_16x16x32_bf16(a1, b, acc[1][h][1], 0, 0, 0);
            }
        }
    }

    // ---- epilogue: rs += xQ_frag * x  (D: col = lane&15, row = kg*4 + j) ----
    float rs[2][4];
#pragma unroll
    for (int m = 0; m < 2; ++m)
#pragma unroll
        for (int j = 0; j < 4; ++j) rs[m][j] = 0.0f;

#pragma unroll
    for (int pi = 0; pi < 2; ++pi) {
        const int p = pi ? p1 : p0;
#pragma unroll
        for (int h = 0; h < 2; ++h) {
            const int c0 = p * 32 + h * 16;
#pragma unroll
            for (int m = 0; m < 2; ++m) {
#pragma unroll
                for (int j = 0; j < 4; ++j) {
                    int r = m * 16 + kg * 4 + j;
                    int e = (r * FDIM + c0 + col) ^ ((r & 15) << 3);
                    rs[m][j] += acc[pi][h][m][j] * (float)xs[e];
                }
            }
        }
    }

    // ---- reduce across 16 cols (lanes sharing kg) ----
#pragma unroll
    for (int m = 0; m < 2; ++m) {
#pragma unroll
        for (int j = 0; j < 4; ++j) {
            float v2 = rs[m][j];
            v2 += __shfl_xor(v2, 1);
            v2 += __shfl_xor(v2, 2);
            v2 += __shfl_xor(v2, 4);
            v2 += __shfl_xor(v2, 8);
            rs[m][j] = v2;
        }
    }
    if (col == 0) {
#pragma unroll
        for (int m = 0; m < 2; ++m)
#pragma unroll
            for (int j = 0; j < 4; ++j)
                rsum[w][m * 16 + kg * 4 + j] = rs[m][j];
    }
    __syncthreads();

    if (tid < BM) {
        float s = 0.0f;
#pragma unroll
        for (int ww = 0; ww < 8; ++ww) s += rsum[ww][tid];
        out[blk + tid] = s;
    }
}

extern "C" void kernel_launch(void* const* d_in, const int* in_sizes, int n_in,
                              void* d_out, int out_size, void* d_ws, size_t ws_size,
                              hipStream_t stream) {
    const float* x = (const float*)d_in[0];
    const float* Q = (const float*)d_in[1];
    float* out = (float*)d_out;
    bf16_t* Qt = (bf16_t*)d_ws;        // 512*512*2 = 512 KB scratch

    const int B = in_sizes[0] / FDIM;  // 131072

    dim3 tgrid(FDIM / 32, FDIM / 32);
    qtrans_kernel<<<tgrid, 256, 0, stream>>>(Q, Qt);
    bilinear_kernel<<<B / BM, NTHR, 0, stream>>>(x, Qt, out);
}